// Round 1
// baseline (614.920 us; speedup 1.0000x reference)
//
#include <hip/hip_runtime.h>

#define B_ 256
#define T_ 512
#define F_ 64
#define U_ 128

// DPP-based add of a cross-lane value (VALU pipe, avoids DS-pipe shuffles).
__device__ __forceinline__ float dpp_add_x(float v, const int ctrl) {
  // mov_dpp of v with given control, then add. row_mask=0xf bank_mask=0xf bound_ctrl=true
  int t;
  switch (ctrl) {
    case 0xB1:  t = __builtin_amdgcn_update_dpp(0, __float_as_int(v), 0xB1, 0xf, 0xf, true); break;  // quad_perm [1,0,3,2]
    case 0x4E:  t = __builtin_amdgcn_update_dpp(0, __float_as_int(v), 0x4E, 0xf, 0xf, true); break;  // quad_perm [2,3,0,1]
    default:    t = __builtin_amdgcn_update_dpp(0, __float_as_int(v), 0x141, 0xf, 0xf, true); break; // row_half_mirror
  }
  return v + __int_as_float(t);
}

// Sum across each aligned group of 8 lanes; all 8 lanes end with the full sum.
__device__ __forceinline__ float red8(float v) {
  v = dpp_add_x(v, 0xB1);   // xor 1
  v = dpp_add_x(v, 0x4E);   // xor 2
  v = dpp_add_x(v, 0x141);  // combine halves of 8 (mirror within half-row)
  return v;
}

__device__ __forceinline__ float sigmoidf_(float x) {
  return 1.0f / (1.0f + __expf(-x));
}

__global__ __launch_bounds__(512, 2) void grud_kernel(
    const float* __restrict__ x, const float* __restrict__ m,
    const float* __restrict__ delta_t,
    const float* __restrict__ Wz, const float* __restrict__ Uz, const float* __restrict__ bz,
    const float* __restrict__ Wr, const float* __restrict__ Ur, const float* __restrict__ br,
    const float* __restrict__ Wh, const float* __restrict__ Uh, const float* __restrict__ bh,
    const float* __restrict__ gxd, const float* __restrict__ ghd,
    const float* __restrict__ mi,
    float* __restrict__ out)
{
  const int tid = threadIdx.x;
  const int b   = blockIdx.x;
  const int kq  = tid & 7;    // k-span owner: k in [16*kq, 16*kq+16)
  const int ug  = tid >> 3;   // output pair owner: u in {2*ug, 2*ug+1}
  const int u0  = 2 * ug;

  __shared__ float s_xdec[32 * F_];  // decayed/imputed x for a 32-step chunk
  __shared__ float s_dt[32];
  __shared__ float s_h[U_];
  __shared__ float s_hdec[U_];
  __shared__ float s_rh[U_];

  // ---- preload weights into registers ----
  float2 uzr[16], urr[16], uhr[16];
  {
    const float2* Uz2 = (const float2*)Uz;
    const float2* Ur2 = (const float2*)Ur;
    const float2* Uh2 = (const float2*)Uh;
#pragma unroll
    for (int i = 0; i < 16; ++i) {
      const int k = 16 * kq + i;
      const int o = (k * U_ + u0) >> 1;
      uzr[i] = Uz2[o];
      urr[i] = Ur2[o];
      uhr[i] = Uh2[o];
    }
  }
  float2 wzr[8], wrr[8], whr[8];
  {
    const float2* Wz2 = (const float2*)Wz;
    const float2* Wr2 = (const float2*)Wr;
    const float2* Wh2 = (const float2*)Wh;
#pragma unroll
    for (int i = 0; i < 8; ++i) {
      const int f = 8 * kq + i;
      const int o = (f * U_ + u0) >> 1;
      wzr[i] = Wz2[o];
      wrr[i] = Wr2[o];
      whr[i] = Wh2[o];
    }
  }
  const float2 bzv = ((const float2*)bz)[ug];
  const float2 brv = ((const float2*)br)[ug];
  const float2 bhv = ((const float2*)bh)[ug];
  const float  ghd_t = (tid < U_) ? ghd[tid] : 0.0f;

  if (tid < U_) s_h[tid] = 0.0f;

  // persisted across phases for the kq==0 writer lanes
  float z0 = 0.f, z1 = 0.f;
  float2 hd2 = make_float2(0.f, 0.f);

  for (int t0 = 0; t0 < T_; t0 += 32) {
    // ---- stage chunk: dt + pre-decayed x into LDS ----
    if (tid < 32) s_dt[tid] = delta_t[b * T_ + t0 + tid];
    {
      const int idx0 = tid * 4;              // 0..2044, covers 32*64 elements
      const int tt   = idx0 >> 6;            // timestep within chunk
      const int f0   = idx0 & 63;
      const float dtv = delta_t[b * T_ + t0 + tt];
      const float4 xv  = *(const float4*)(x  + (size_t)b * T_ * F_ + (t0 + tt) * F_ + f0);
      const float4 mv  = *(const float4*)(m  + (size_t)b * T_ * F_ + (t0 + tt) * F_ + f0);
      const float4 gv  = *(const float4*)(gxd + f0);
      const float4 miv = *(const float4*)(mi  + f0);
      float4 xd;
      {
        float gx;
        gx   = __expf(-fmaxf(gv.x, 0.0f) * dtv);
        xd.x = mv.x * xv.x + (1.0f - mv.x) * (gx * xv.x + (1.0f - gx) * miv.x);
        gx   = __expf(-fmaxf(gv.y, 0.0f) * dtv);
        xd.y = mv.y * xv.y + (1.0f - mv.y) * (gx * xv.y + (1.0f - gx) * miv.y);
        gx   = __expf(-fmaxf(gv.z, 0.0f) * dtv);
        xd.z = mv.z * xv.z + (1.0f - mv.z) * (gx * xv.z + (1.0f - gx) * miv.z);
        gx   = __expf(-fmaxf(gv.w, 0.0f) * dtv);
        xd.w = mv.w * xv.w + (1.0f - mv.w) * (gx * xv.w + (1.0f - gx) * miv.w);
      }
      *(float4*)(s_xdec + idx0) = xd;
    }
    __syncthreads();

    for (int tc = 0; tc < 32; ++tc) {
      // ---- Phase A: h_dec = gamma_h * h ----
      if (tid < U_) {
        const float dt = s_dt[tc];
        const float gh = __expf(-fmaxf(ghd_t, 0.0f) * dt);
        s_hdec[tid] = gh * s_h[tid];
      }
      __syncthreads();

      // ---- Phase B: z and r gates ----
      float hv[16];
      {
        const float4* hd4 = (const float4*)s_hdec;
        const float4 a0 = hd4[4 * kq + 0];
        const float4 a1 = hd4[4 * kq + 1];
        const float4 a2 = hd4[4 * kq + 2];
        const float4 a3 = hd4[4 * kq + 3];
        hv[0]=a0.x; hv[1]=a0.y; hv[2]=a0.z; hv[3]=a0.w;
        hv[4]=a1.x; hv[5]=a1.y; hv[6]=a1.z; hv[7]=a1.w;
        hv[8]=a2.x; hv[9]=a2.y; hv[10]=a2.z; hv[11]=a2.w;
        hv[12]=a3.x; hv[13]=a3.y; hv[14]=a3.z; hv[15]=a3.w;
      }
      float xf[8];
      {
        const float4* xd4 = (const float4*)(s_xdec + tc * F_);
        const float4 x0 = xd4[2 * kq + 0];
        const float4 x1 = xd4[2 * kq + 1];
        xf[0]=x0.x; xf[1]=x0.y; xf[2]=x0.z; xf[3]=x0.w;
        xf[4]=x1.x; xf[5]=x1.y; xf[6]=x1.z; xf[7]=x1.w;
      }
      float az0 = 0.f, az1 = 0.f, ar0 = 0.f, ar1 = 0.f;
#pragma unroll
      for (int i = 0; i < 16; ++i) {
        az0 = fmaf(hv[i], uzr[i].x, az0);
        az1 = fmaf(hv[i], uzr[i].y, az1);
        ar0 = fmaf(hv[i], urr[i].x, ar0);
        ar1 = fmaf(hv[i], urr[i].y, ar1);
      }
#pragma unroll
      for (int i = 0; i < 8; ++i) {
        az0 = fmaf(xf[i], wzr[i].x, az0);
        az1 = fmaf(xf[i], wzr[i].y, az1);
        ar0 = fmaf(xf[i], wrr[i].x, ar0);
        ar1 = fmaf(xf[i], wrr[i].y, ar1);
      }
      az0 = red8(az0); az1 = red8(az1);
      ar0 = red8(ar0); ar1 = red8(ar1);
      z0 = sigmoidf_(az0 + bzv.x);
      z1 = sigmoidf_(az1 + bzv.y);
      const float r0 = sigmoidf_(ar0 + brv.x);
      const float r1 = sigmoidf_(ar1 + brv.y);
      if (kq == 0) {
        hd2 = ((const float2*)s_hdec)[ug];
        float2 rh2;
        rh2.x = r0 * hd2.x;
        rh2.y = r1 * hd2.y;
        ((float2*)s_rh)[ug] = rh2;
      }
      __syncthreads();

      // ---- Phase C: candidate + update ----
      float rv[16];
      {
        const float4* rh4 = (const float4*)s_rh;
        const float4 c0 = rh4[4 * kq + 0];
        const float4 c1 = rh4[4 * kq + 1];
        const float4 c2 = rh4[4 * kq + 2];
        const float4 c3 = rh4[4 * kq + 3];
        rv[0]=c0.x; rv[1]=c0.y; rv[2]=c0.z; rv[3]=c0.w;
        rv[4]=c1.x; rv[5]=c1.y; rv[6]=c1.z; rv[7]=c1.w;
        rv[8]=c2.x; rv[9]=c2.y; rv[10]=c2.z; rv[11]=c2.w;
        rv[12]=c3.x; rv[13]=c3.y; rv[14]=c3.z; rv[15]=c3.w;
      }
      float ah0 = 0.f, ah1 = 0.f;
#pragma unroll
      for (int i = 0; i < 16; ++i) {
        ah0 = fmaf(rv[i], uhr[i].x, ah0);
        ah1 = fmaf(rv[i], uhr[i].y, ah1);
      }
#pragma unroll
      for (int i = 0; i < 8; ++i) {
        ah0 = fmaf(xf[i], whr[i].x, ah0);
        ah1 = fmaf(xf[i], whr[i].y, ah1);
      }
      ah0 = red8(ah0); ah1 = red8(ah1);
      const float hh0 = tanhf(ah0 + bhv.x);
      const float hh1 = tanhf(ah1 + bhv.y);
      if (kq == 0) {
        const float hn0 = (1.0f - z0) * hd2.x + z0 * hh0;
        const float hn1 = (1.0f - z1) * hd2.y + z1 * hh1;
        ((float2*)s_h)[ug] = make_float2(hn0, hn1);
        *(float2*)(out + (size_t)(b * T_ + t0 + tc) * U_ + u0) = make_float2(hn0, hn1);
      }
      __syncthreads();
    }
  }
}

extern "C" void kernel_launch(void* const* d_in, const int* in_sizes, int n_in,
                              void* d_out, int out_size, void* d_ws, size_t ws_size,
                              hipStream_t stream) {
  const float* x   = (const float*)d_in[0];
  const float* m   = (const float*)d_in[1];
  const float* dt  = (const float*)d_in[2];
  const float* Wz  = (const float*)d_in[3];
  const float* Uz  = (const float*)d_in[4];
  const float* bz  = (const float*)d_in[5];
  const float* Wr  = (const float*)d_in[6];
  const float* Ur  = (const float*)d_in[7];
  const float* br  = (const float*)d_in[8];
  const float* Wh  = (const float*)d_in[9];
  const float* Uh  = (const float*)d_in[10];
  const float* bh  = (const float*)d_in[11];
  const float* gxd = (const float*)d_in[12];
  const float* ghd = (const float*)d_in[13];
  const float* mi  = (const float*)d_in[14];

  grud_kernel<<<dim3(B_), dim3(512), 0, stream>>>(
      x, m, dt, Wz, Uz, bz, Wr, Ur, br, Wh, Uh, bh, gxd, ghd, mi, (float*)d_out);
}

// Round 2
// 423.411 us; speedup vs baseline: 1.4523x; 1.4523x over previous
//
#include <hip/hip_runtime.h>

#define B_ 256
#define T_ 512
#define F_ 64
#define U_ 128

// Sum across each aligned quad of lanes via DPP quad_perm (VALU pipe only).
__device__ __forceinline__ float red4(float v) {
  int t = __builtin_amdgcn_update_dpp(0, __float_as_int(v), 0xB1, 0xF, 0xF, true); // [1,0,3,2]
  v += __int_as_float(t);
  t = __builtin_amdgcn_update_dpp(0, __float_as_int(v), 0x4E, 0xF, 0xF, true);     // [2,3,0,1]
  v += __int_as_float(t);
  return v;
}

__device__ __forceinline__ float fast_sig(float x) {
  return __builtin_amdgcn_rcpf(1.0f + __expf(-x));
}
__device__ __forceinline__ float fast_tanh(float x) {
  // 1 - 2/(1+e^{2x}); safe at large |x| (inf -> 1, 0 -> -1), no NaN.
  return fmaf(-2.0f, __builtin_amdgcn_rcpf(1.0f + __expf(2.0f * x)), 1.0f);
}

// Stage a 128x128 matrix into s_pool (coalesced), then gather this thread's
// rotated k-slots: slot j holds rows kb..kb+3, col ow, kb = 32*kq + 4*((2*kq+j)&7).
#define STAGE_U(SRC, DST)                                                   \
  {                                                                         \
    float4* p4 = (float4*)s_pool;                                           \
    const float4* g4 = (const float4*)(SRC);                                \
    _Pragma("unroll") for (int i = 0; i < 8; ++i)                           \
        p4[tid + i * 512] = g4[tid + i * 512];                              \
    __syncthreads();                                                        \
    _Pragma("unroll") for (int j = 0; j < 8; ++j) {                         \
      const int kb = 32 * kq + 4 * ((2 * kq + j) & 7);                      \
      DST[j].x = s_pool[(kb + 0) * U_ + ow];                                \
      DST[j].y = s_pool[(kb + 1) * U_ + ow];                                \
      DST[j].z = s_pool[(kb + 2) * U_ + ow];                                \
      DST[j].w = s_pool[(kb + 3) * U_ + ow];                                \
    }                                                                       \
    __syncthreads();                                                        \
  }

// Stage a 64x128 matrix, gather plain f-slots: slot j = rows 16*kq+4j.., col ow.
#define STAGE_W(SRC, DST)                                                   \
  {                                                                         \
    float4* p4 = (float4*)s_pool;                                           \
    const float4* g4 = (const float4*)(SRC);                                \
    _Pragma("unroll") for (int i = 0; i < 4; ++i)                           \
        p4[tid + i * 512] = g4[tid + i * 512];                              \
    __syncthreads();                                                        \
    _Pragma("unroll") for (int j = 0; j < 4; ++j) {                         \
      const int fb = 16 * kq + 4 * j;                                       \
      DST[j].x = s_pool[(fb + 0) * U_ + ow];                                \
      DST[j].y = s_pool[(fb + 1) * U_ + ow];                                \
      DST[j].z = s_pool[(fb + 2) * U_ + ow];                                \
      DST[j].w = s_pool[(fb + 3) * U_ + ow];                                \
    }                                                                       \
    __syncthreads();                                                        \
  }

__global__ __launch_bounds__(512, 2) void grud_kernel(
    const float* __restrict__ x, const float* __restrict__ m,
    const float* __restrict__ delta_t,
    const float* __restrict__ Wz, const float* __restrict__ Uz, const float* __restrict__ bz,
    const float* __restrict__ Wr, const float* __restrict__ Ur, const float* __restrict__ br,
    const float* __restrict__ Wh, const float* __restrict__ Uh, const float* __restrict__ bh,
    const float* __restrict__ gxd, const float* __restrict__ ghd,
    const float* __restrict__ mi,
    float* __restrict__ out)
{
  const int tid = threadIdx.x;
  const int b   = blockIdx.x;
  const int kq  = tid & 3;   // k-span: k in [32*kq, 32*kq+32); f in [16*kq, 16*kq+16)
  const int ow  = tid >> 2;  // owned output u

  __shared__ float s_pool[U_ * U_];   // 64 KB weight staging (reused per matrix)
  __shared__ float s_xdec[32 * F_];   // 8 KB: decayed x for a 32-step chunk
  __shared__ float s_hist[32 * U_];   // 16 KB: h outputs for the chunk
  __shared__ float s_hdx[2 * U_];     // h_dec, span-duplicated (conflict-free reads)
  __shared__ float s_rhx[2 * U_];     // r*h_dec, span-duplicated
  __shared__ float s_dt[36];

  float4 wz[8], wr[8], wh[8];    // U_z/U_r/U_h rows (rotated slots), col ow: 96 regs
  float4 wzx[4], wrx[4], whx[4]; // W_z/W_r/W_h rows, col ow: 48 regs

  STAGE_U(Uz, wz)
  STAGE_U(Ur, wr)
  STAGE_U(Uh, wh)
  STAGE_W(Wz, wzx)
  STAGE_W(Wr, wrx)
  STAGE_W(Wh, whx)

  const float bz_o  = bz[ow];
  const float br_o  = br[ow];
  const float bh_o  = bh[ow];
  const float ghd_o = fmaxf(ghd[ow], 0.0f);

  if (tid < 2 * U_) s_hdx[tid] = 0.0f;  // h0 = 0 -> h_dec = 0

  const float4* hb4 = (const float4*)(s_hdx + 72 * kq);  // rotated base, 16B-aligned
  const float4* rb4 = (const float4*)(s_rhx + 72 * kq);
  const int owq = 64 * (ow >> 5) + (ow & 31);            // this output's slot in X-layout

  for (int t0 = 0; t0 < T_; t0 += 32) {
    // ---- stage chunk: dt[33] + pre-decayed x ----
    if (tid < 33) {
      const int t = t0 + tid;
      s_dt[tid] = (t < T_) ? delta_t[b * T_ + t] : 0.0f;
    }
    {
      const int idx0 = tid * 4;          // covers 32*64 floats
      const int tt   = idx0 >> 6;
      const int f0   = idx0 & 63;
      const float dtv = delta_t[b * T_ + t0 + tt];
      const float4 xv  = *(const float4*)(x  + (size_t)(b * T_ + t0 + tt) * F_ + f0);
      const float4 mv  = *(const float4*)(m  + (size_t)(b * T_ + t0 + tt) * F_ + f0);
      const float4 gv  = *(const float4*)(gxd + f0);
      const float4 miv = *(const float4*)(mi  + f0);
      float4 xd; float gx;
      gx   = __expf(-fmaxf(gv.x, 0.0f) * dtv);
      xd.x = mv.x * xv.x + (1.0f - mv.x) * (gx * xv.x + (1.0f - gx) * miv.x);
      gx   = __expf(-fmaxf(gv.y, 0.0f) * dtv);
      xd.y = mv.y * xv.y + (1.0f - mv.y) * (gx * xv.y + (1.0f - gx) * miv.y);
      gx   = __expf(-fmaxf(gv.z, 0.0f) * dtv);
      xd.z = mv.z * xv.z + (1.0f - mv.z) * (gx * xv.z + (1.0f - gx) * miv.z);
      gx   = __expf(-fmaxf(gv.w, 0.0f) * dtv);
      xd.w = mv.w * xv.w + (1.0f - mv.w) * (gx * xv.w + (1.0f - gx) * miv.w);
      *(float4*)(s_xdec + idx0) = xd;
    }
    __syncthreads();

    for (int tc = 0; tc < 32; ++tc) {
      // ---- Phase B: z, r gates (+ W_h*x partial) ----
      float az = 0.0f, ar = 0.0f, axh = 0.0f;
#pragma unroll
      for (int j = 0; j < 8; ++j) {
        const float4 h4 = hb4[j];
        az = fmaf(h4.x, wz[j].x, az); az = fmaf(h4.y, wz[j].y, az);
        az = fmaf(h4.z, wz[j].z, az); az = fmaf(h4.w, wz[j].w, az);
        ar = fmaf(h4.x, wr[j].x, ar); ar = fmaf(h4.y, wr[j].y, ar);
        ar = fmaf(h4.z, wr[j].z, ar); ar = fmaf(h4.w, wr[j].w, ar);
      }
      {
        const float4* xr4 = (const float4*)(s_xdec + tc * F_ + 16 * kq);
#pragma unroll
        for (int j = 0; j < 4; ++j) {
          const float4 x4 = xr4[j];
          az  = fmaf(x4.x, wzx[j].x, az);  az  = fmaf(x4.y, wzx[j].y, az);
          az  = fmaf(x4.z, wzx[j].z, az);  az  = fmaf(x4.w, wzx[j].w, az);
          ar  = fmaf(x4.x, wrx[j].x, ar);  ar  = fmaf(x4.y, wrx[j].y, ar);
          ar  = fmaf(x4.z, wrx[j].z, ar);  ar  = fmaf(x4.w, wrx[j].w, ar);
          axh = fmaf(x4.x, whx[j].x, axh); axh = fmaf(x4.y, whx[j].y, axh);
          axh = fmaf(x4.z, whx[j].z, axh); axh = fmaf(x4.w, whx[j].w, axh);
        }
      }
      az = red4(az); ar = red4(ar);
      const float z  = fast_sig(az + bz_o);
      const float r  = fast_sig(ar + br_o);
      const float hd = s_hdx[owq];
      if (kq == 0) {
        const float rh = r * hd;
        s_rhx[owq]      = rh;
        s_rhx[owq + 32] = rh;
      }
      __syncthreads();

      // ---- Phase C: candidate + update ----
      float ah = axh;
#pragma unroll
      for (int j = 0; j < 8; ++j) {
        const float4 r4 = rb4[j];
        ah = fmaf(r4.x, wh[j].x, ah); ah = fmaf(r4.y, wh[j].y, ah);
        ah = fmaf(r4.z, wh[j].z, ah); ah = fmaf(r4.w, wh[j].w, ah);
      }
      ah = red4(ah);
      const float hh = fast_tanh(ah + bh_o);
      const float hn = (1.0f - z) * hd + z * hh;
      if (kq == 0) {
        s_hist[tc * U_ + ow] = hn;
        const float gh  = __expf(-ghd_o * s_dt[tc + 1]);
        const float hdn = gh * hn;
        s_hdx[owq]      = hdn;
        s_hdx[owq + 32] = hdn;
      }
      __syncthreads();
    }

    // ---- flush chunk history (coalesced) ----
    {
      const float4* h4 = (const float4*)s_hist;
      float4* o4 = (float4*)(out + (size_t)(b * T_ + t0) * U_);
      o4[tid]       = h4[tid];
      o4[tid + 512] = h4[tid + 512];
    }
  }
}

extern "C" void kernel_launch(void* const* d_in, const int* in_sizes, int n_in,
                              void* d_out, int out_size, void* d_ws, size_t ws_size,
                              hipStream_t stream) {
  const float* x   = (const float*)d_in[0];
  const float* m   = (const float*)d_in[1];
  const float* dt  = (const float*)d_in[2];
  const float* Wz  = (const float*)d_in[3];
  const float* Uz  = (const float*)d_in[4];
  const float* bz  = (const float*)d_in[5];
  const float* Wr  = (const float*)d_in[6];
  const float* Ur  = (const float*)d_in[7];
  const float* br  = (const float*)d_in[8];
  const float* Wh  = (const float*)d_in[9];
  const float* Uh  = (const float*)d_in[10];
  const float* bh  = (const float*)d_in[11];
  const float* gxd = (const float*)d_in[12];
  const float* ghd = (const float*)d_in[13];
  const float* mi  = (const float*)d_in[14];

  grud_kernel<<<dim3(B_), dim3(512), 0, stream>>>(
      x, m, dt, Wz, Uz, bz, Wr, Ur, br, Wh, Uh, bh, gxd, ghd, mi, (float*)d_out);
}